// Round 15
// baseline (208.467 us; speedup 1.0000x reference)
//
#include <hip/hip_runtime.h>

#define NFR 8
#define CDIM 128
#define HH 96
#define WW 96
#define NB 4
#define HWSZ 9216        // HH*WW
#define NBLK 2304        // NB*HH*(WW/16)
#define NXCD 8
#define CPX (NBLK / NXCD)  // 288

typedef __attribute__((ext_vector_type(8))) short bf16x8;
typedef __attribute__((ext_vector_type(4))) float f32x4;
typedef __attribute__((ext_vector_type(2))) float f32x2;
typedef __attribute__((ext_vector_type(2))) __bf16 bf16x2;

union FragU { uint4 u; bf16x8 v; };

__device__ inline float bf2f(unsigned short h) {
    unsigned int x = ((unsigned int)h) << 16;
    float f; __builtin_memcpy(&f, &x, 4); return f;
}
__device__ inline unsigned short f2bf(float f) {
    unsigned int x; __builtin_memcpy(&x, &f, 4);
    return (unsigned short)((x + 0x7FFFu + ((x >> 16) & 1u)) >> 16);
}
__device__ inline unsigned int packbf(float a, float b) {
    return (unsigned int)f2bf(a) | ((unsigned int)f2bf(b) << 16);
}
// HW path: compiler emits v_cvt_pk_bf16_f32 (RNE, same results as packbf)
__device__ inline unsigned int cvt2(float a, float b) {
    f32x2 f = {a, b};
    bf16x2 h = __builtin_convertvector(f, bf16x2);
    unsigned int u; __builtin_memcpy(&u, &h, 4); return u;
}
__device__ inline unsigned short cvt1(float a) {
    __bf16 h = (__bf16)a;
    unsigned short s; __builtin_memcpy(&s, &h, 2); return s;
}
// fragment-permutation position of channel-within-32 (even for even c5)
__device__ inline int posmap(int c5) {
    return (c5 < 16) ? (((c5 >> 2) << 3) + (c5 & 3))
                     : ((((c5 & 15) >> 2) << 3) + 4 + (c5 & 3));
}

// ---------------------------------------------------------------------------
// ws layout (uint4 units of 16B):
//   [0,    4096) : qk A-frags   ((hd*2+three)*4+ks)*64 + lane   (three: 0=q,1=k)
//                  q fragments pre-scaled by 0.25 (attention SCALE folded in)
//   [4096, 6144) : v  B-frags   (hd*4+ks)*64 + lane
//   [6144, 8192) : proj B-frags (nt*4+ks)*64 + lane
//   [8192, 8208) : gamma bf16 frags (ks*4+lg), [8208, 8224): beta bf16 frags
// Fragment element e (0..7) of (ks,lg): channel c = ks*32+lg*4+(e&3)+((e>>2)<<4)
// ---------------------------------------------------------------------------
__global__ __launch_bounds__(256)
void repack_k(const float* __restrict__ wqkv, const float* __restrict__ wproj,
              const float* __restrict__ gamma, const float* __restrict__ beta,
              unsigned short* __restrict__ ws)
{
    int gid = blockIdx.x * 256 + threadIdx.x;
    uint4* wsq = (uint4*)ws;
    int l = gid & 63, lr = l & 15, lg = (l >> 4) & 3;
    if (gid < 8192) {
        int unit = gid >> 6;
        int col, ks, stride;
        float scale = 1.0f;
        const float* src;
        if (unit < 64) {              // qk A-frags: A[m=col][k=c] = wqkv[c][col]
            int t = unit >> 2; ks = unit & 3;
            int hd = t >> 1, three = t & 1;
            col = three * 128 + hd * 16 + lr;
            src = wqkv; stride = 384;
            if (three == 0) scale = 0.25f;   // fold SCALE into q
        } else if (unit < 96) {       // v B-frags: B[k=c][n] = wqkv[c][256+hd*16+n]
            int u2 = unit - 64; int hd = u2 >> 2; ks = u2 & 3;
            col = 256 + hd * 16 + lr;
            src = wqkv; stride = 384;
        } else {                      // proj B-frags: B[k=c][n] = wproj[c][n]
            int u3 = unit - 96; int nt = u3 >> 2; ks = u3 & 3;
            col = nt * 16 + lr;
            src = wproj; stride = 128;
        }
        unsigned int dw[4];
        #pragma unroll
        for (int i = 0; i < 4; ++i) {
            int e0 = 2 * i, e1 = 2 * i + 1;
            int c0 = ks * 32 + lg * 4 + (e0 & 3) + ((e0 >> 2) << 4);
            int c1 = ks * 32 + lg * 4 + (e1 & 3) + ((e1 >> 2) << 4);
            dw[i] = packbf(src[c0 * stride + col] * scale, src[c1 * stride + col] * scale);
        }
        uint4 o; o.x = dw[0]; o.y = dw[1]; o.z = dw[2]; o.w = dw[3];
        wsq[gid] = o;
    } else if (gid < 8192 + 32) {
        int t = gid - 8192;           // 0..15 gamma frags, 16..31 beta frags
        int isb = t >> 4;
        int unit = t & 15;
        int ks2 = unit >> 2, lg2 = unit & 3;
        const float* src2 = isb ? beta : gamma;
        unsigned int dw[4];
        #pragma unroll
        for (int i = 0; i < 4; ++i) {
            int e0 = 2 * i, e1 = 2 * i + 1;
            int c0 = ks2 * 32 + lg2 * 4 + (e0 & 3) + ((e0 >> 2) << 4);
            int c1 = ks2 * 32 + lg2 * 4 + (e1 & 3) + ((e1 >> 2) << 4);
            dw[i] = packbf(src2[c0], src2[c1]);
        }
        uint4 o; o.x = dw[0]; o.y = dw[1]; o.z = dw[2]; o.w = dw[3];
        wsq[8192 + t] = o;
    }
}

// all-register attention for one head, one 64-row group (SCALE pre-folded)
__device__ inline f32x4 attn_ov(f32x4 q, f32x4 k, f32x4 v, bool valid) {
    FragU qb, kb, vb;
    qb.u.x = cvt2(q.x, q.y); qb.u.y = cvt2(q.z, q.w); qb.u.z = 0; qb.u.w = 0;
    kb.u.x = cvt2(k.x, k.y); kb.u.y = cvt2(k.z, k.w); kb.u.z = 0; kb.u.w = 0;
    vb.u.x = cvt2(v.x, v.y); vb.u.y = cvt2(v.z, v.w); vb.u.z = 0; vb.u.w = 0;
    f32x4 zz = {0,0,0,0};
    // S^T = K·Q^T (K=16, upper half zero): lane holds S[q=lr][k=lg*4+j]
    f32x4 st = __builtin_amdgcn_mfma_f32_16x16x32_bf16(kb.v, qb.v, zz, 0, 0, 0);
    float sc0 = st.x, sc1 = st.y, sc2 = st.z, sc3 = st.w;
    float m = valid ? fmaxf(fmaxf(sc0, sc1), fmaxf(sc2, sc3)) : -3.0e38f;
    m = fmaxf(m, __shfl_xor(m, 16));
    float e0 = valid ? __expf(sc0 - m) : 0.f, e1 = valid ? __expf(sc1 - m) : 0.f;
    float e2 = valid ? __expf(sc2 - m) : 0.f, e3 = valid ? __expf(sc3 - m) : 0.f;
    float sm = e0 + e1 + e2 + e3; sm += __shfl_xor(sm, 16);
    float inv = 1.f / sm;
    FragU pb;
    pb.u.x = cvt2(valid ? e0 * inv : 0.f, valid ? e1 * inv : 0.f);
    pb.u.y = cvt2(valid ? e2 * inv : 0.f, valid ? e3 * inv : 0.f);
    pb.u.z = 0; pb.u.w = 0;
    // O^T = V^T·P^T: lane holds O[q=lr][d=lg*4+j]
    return __builtin_amdgcn_mfma_f32_16x16x32_bf16(vb.v, pb.v, zz, 0, 0, 0);
}

// in-register LayerNorm over one 64-row group's fragments.
// Row wv*16+lr lives across lanes {lr, lr+16, lr+32, lr+48} (lg=0..3);
// shfl_xor(16)+shfl_xor(32) reduce across the row.
__device__ inline void ln_reg(FragU* xf, const uint4* gf, const uint4* bfr) {
    float s = 0.f, ss = 0.f;
    #pragma unroll
    for (int ks = 0; ks < 4; ++ks) {
        const unsigned short* e = (const unsigned short*)&xf[ks];
        #pragma unroll
        for (int j = 0; j < 8; ++j) { float x = bf2f(e[j]); s += x; ss += x * x; }
    }
    s += __shfl_xor(s, 16); ss += __shfl_xor(ss, 16);
    s += __shfl_xor(s, 32); ss += __shfl_xor(ss, 32);
    float mu = s * (1.f / 128.f);
    float var = ss * (1.f / 128.f) - mu * mu;
    float rstd = rsqrtf(var + 1e-5f);
    float mr = mu * rstd;
    #pragma unroll
    for (int ks = 0; ks < 4; ++ks) {
        const unsigned short* e = (const unsigned short*)&xf[ks];
        const unsigned short* g = (const unsigned short*)&gf[ks];
        const unsigned short* b = (const unsigned short*)&bfr[ks];
        unsigned int dw[4];
        #pragma unroll
        for (int i = 0; i < 4; ++i) {
            float x0 = bf2f(e[2 * i])     * rstd - mr;
            float x1 = bf2f(e[2 * i + 1]) * rstd - mr;
            dw[i] = cvt2(x0 * bf2f(g[2 * i])     + bf2f(b[2 * i]),
                         x1 * bf2f(g[2 * i + 1]) + bf2f(b[2 * i + 1]));
        }
        xf[ks].u.x = dw[0]; xf[ks].u.y = dw[1]; xf[ks].u.z = dw[2]; xf[ks].u.w = dw[3];
    }
}

// global slot index (uint4 units) for weight slot s (0..11) of head hd:
// s 0..7 = qk A-frags, s 8..11 = v B-frags
__device__ inline int wslot(int hd, int s) {
    return (s < 8) ? (hd * 8 + s) * 64 : 4096 + (hd * 4 + (s - 8)) * 64;
}

// ---------------------------------------------------------------------------
// xln LDS: 32KB. Phase A: staged features (2 groups). Phase B (head loop):
// double-buffered weight slices buf0 @u4[512], buf1 @u4[1280] (12KB each).
// Phase C (proj/epilogue): out_t (32KB). Barriers separate the phases.
// ---------------------------------------------------------------------------
__global__ __launch_bounds__(256, 4)
void cfa_main(const float* __restrict__ feat, const float* __restrict__ bproj,
              const unsigned short* __restrict__ ws, float* __restrict__ outp)
{
    __shared__ uint4 xlnU4[2048];                    // 32 KB
    unsigned short* xln16 = (unsigned short*)xlnU4;
    unsigned int*   xln32 = (unsigned int*)xlnU4;

    const int tid = threadIdx.x;
    const int blk = (int)(blockIdx.x % NXCD) * CPX + (int)blockIdx.x / NXCD;
    const int wt = blk % 6, h = (blk / 6) % 96, b = blk / (6 * 96);
    const int base = ((b * NFR) * CDIM) * HWSZ + h * WW + wt * 16;

    // ---- phase 1: stage 16 pixels (raw bf16); 4 lanes per (n,c)-row chunk ----
    #pragma unroll
    for (int it = 0; it < 8; ++it) {
        int t = it * 256 + tid;                      // 0..2047
        int pq = t & 3;
        int pr = t >> 2;                             // 0..511 = n*64 + cpair
        int n = pr >> 6;
        int c = (pr & 63) * 2;                       // even channel
        const float* src = feat + base + (n * CDIM + c) * HWSZ + pq * 4;
        float4 f0 = *(const float4*)src;             // ch c,   px pq*4..pq*4+3
        float4 f1 = *(const float4*)(src + HWSZ);    // ch c+1, same pixels
        int ks = c >> 5;
        int pos = posmap(c & 31);                    // even; pos(c+1)=pos+1
        const float* a0 = (const float*)&f0;
        const float* a1 = (const float*)&f1;
        #pragma unroll
        for (int j = 0; j < 4; ++j) {
            int p = pq * 4 + j;
            int g = p >> 3, pin = p & 7;
            xln32[(g * 8192 + ks * 2048 + (pin * 8 + n) * 32 + pos) >> 1] =
                cvt2(a0[j], a1[j]);
        }
    }
    __syncthreads();                                 // B1: staging visible

    const int wv = tid >> 6, l = tid & 63, lr = l & 15, lg = l >> 4;
    const uint4* wsq = (const uint4*)ws;

    // ---- prefetch head-0 weight slots NOW (L2 latency hides under LN) ----
    uint4 h0s0 = wsq[wslot(0, wv * 3 + 0) + l];
    uint4 h0s1 = wsq[wslot(0, wv * 3 + 1) + l];
    uint4 h0s2 = wsq[wslot(0, wv * 3 + 2) + l];

    // ---- gamma/beta frags ----
    uint4 gf[4], bfx[4];
    #pragma unroll
    for (int ks = 0; ks < 4; ++ks) {
        gf[ks]  = wsq[8192 + ks * 4 + lg];
        bfx[ks] = wsq[8208 + ks * 4 + lg];
    }

    // ---- read raw frags, LayerNorm in registers ----
    FragU xf0[4], xf1[4];
    #pragma unroll
    for (int ks = 0; ks < 4; ++ks) {
        xf0[ks].u = xlnU4[ks * 256 + (wv * 16 + lr) * 4 + lg];
        xf1[ks].u = xlnU4[1024 + ks * 256 + (wv * 16 + lr) * 4 + lg];
    }
    ln_reg(xf0, gf, bfx);
    ln_reg(xf1, gf, bfx);

    __syncthreads();   // B2: all xf reads done -> xlnU4 free for weight dbuf

    // ---- publish head-0 weights into buf0 (prefetched above) ----
    xlnU4[512 + (wv * 3 + 0) * 64 + l] = h0s0;
    xlnU4[512 + (wv * 3 + 1) * 64 + l] = h0s1;
    xlnU4[512 + (wv * 3 + 2) * 64 + l] = h0s2;

    const bool valid = ((lg >> 1) == (lr >> 3));     // same-pixel (q,k) pairs
    FragU pa0[4], pa1[4];
    #pragma unroll
    for (int ks = 0; ks < 4; ++ks) {
        pa0[ks].u.x = 0; pa0[ks].u.y = 0; pa0[ks].u.z = 0; pa0[ks].u.w = 0;
        pa1[ks].u.x = 0; pa1[ks].u.y = 0; pa1[ks].u.z = 0; pa1[ks].u.w = 0;
    }

    // ---- per-head loop: LDS-dbuf weights (global read ONCE per block) ----
    uint4 PBc[4];                                    // proj nt=0 frags (loaded @hd=7)
    float biasc;
    #pragma unroll
    for (int hd = 0; hd < 8; ++hd) {
        __syncthreads();   // staged weights for head hd visible; prev-parity reads done
        const uint4* buf = &xlnU4[(hd & 1) ? 1280 : 512];
        uint4 sn0, sn1, sn2;
        if (hd < 7) {      // issue next head's 3 slot-loads (latency hides under MFMA)
            sn0 = wsq[wslot(hd + 1, wv * 3 + 0) + l];
            sn1 = wsq[wslot(hd + 1, wv * 3 + 1) + l];
            sn2 = wsq[wslot(hd + 1, wv * 3 + 2) + l];
        } else {
            #pragma unroll
            for (int ks = 0; ks < 4; ++ks) PBc[ks] = wsq[6144 + ks * 64 + l];
            biasc = bproj[lr];                       // nt=0: col = lr
        }
        f32x4 q0 = {0,0,0,0}, k0 = {0,0,0,0}, v0 = {0,0,0,0};
        f32x4 q1 = {0,0,0,0}, k1 = {0,0,0,0}, v1 = {0,0,0,0};
        #pragma unroll
        for (int ks = 0; ks < 4; ++ks) {
            FragU A, B, V2;
            A.u  = buf[ks * 64 + l];
            B.u  = buf[(4 + ks) * 64 + l];
            V2.u = buf[(8 + ks) * 64 + l];
            q0 = __builtin_amdgcn_mfma_f32_16x16x32_bf16(A.v,  xf0[ks].v, q0, 0, 0, 0);
            k0 = __builtin_amdgcn_mfma_f32_16x16x32_bf16(B.v,  xf0[ks].v, k0, 0, 0, 0);
            q1 = __builtin_amdgcn_mfma_f32_16x16x32_bf16(A.v,  xf1[ks].v, q1, 0, 0, 0);
            k1 = __builtin_amdgcn_mfma_f32_16x16x32_bf16(B.v,  xf1[ks].v, k1, 0, 0, 0);
            v0 = __builtin_amdgcn_mfma_f32_16x16x32_bf16(xf0[ks].v, V2.v, v0, 0, 0, 0);
            v1 = __builtin_amdgcn_mfma_f32_16x16x32_bf16(xf1[ks].v, V2.v, v1, 0, 0, 0);
        }
        f32x4 o0 = attn_ov(q0, k0, v0, valid);
        f32x4 o1 = attn_ov(q1, k1, v1, valid);
        if ((hd & 1) == 0) {
            pa0[hd >> 1].u.x = cvt2(o0.x, o0.y); pa0[hd >> 1].u.y = cvt2(o0.z, o0.w);
            pa1[hd >> 1].u.x = cvt2(o1.x, o1.y); pa1[hd >> 1].u.y = cvt2(o1.z, o1.w);
        } else {
            pa0[hd >> 1].u.z = cvt2(o0.x, o0.y); pa0[hd >> 1].u.w = cvt2(o0.z, o0.w);
            pa1[hd >> 1].u.z = cvt2(o1.x, o1.y); pa1[hd >> 1].u.w = cvt2(o1.z, o1.w);
        }
        if (hd < 7) {      // publish next head's slots into the other buffer
            int dst = ((hd + 1) & 1) ? 1280 : 512;
            xlnU4[dst + (wv * 3 + 0) * 64 + l] = sn0;
            xlnU4[dst + (wv * 3 + 1) * 64 + l] = sn1;
            xlnU4[dst + (wv * 3 + 2) * 64 + l] = sn2;
        }
    }

    __syncthreads();   // B2b: all dbuf reads done -> xlnU4 reusable as out_t

    // ---- proj GEMM, streamed + prefetched: per nt compute 2 accs -> out_t ----
    unsigned short* out_t = xln16;                   // [g][n][col^n][pix]
    #pragma unroll
    for (int nt = 0; nt < 8; ++nt) {
        uint4 PBn[4]; float biasn;
        if (nt < 7) {
            #pragma unroll
            for (int ks = 0; ks < 4; ++ks) PBn[ks] = wsq[6144 + ((nt + 1) * 4 + ks) * 64 + l];
            biasn = bproj[(nt + 1) * 16 + lr];
        }
        f32x4 a0 = {0,0,0,0}, a1 = {0,0,0,0};
        #pragma unroll
        for (int ks = 0; ks < 4; ++ks) {
            FragU B; B.u = PBc[ks];
            a0 = __builtin_amdgcn_mfma_f32_16x16x32_bf16(pa0[ks].v, B.v, a0, 0, 0, 0);
            a1 = __builtin_amdgcn_mfma_f32_16x16x32_bf16(pa1[ks].v, B.v, a1, 0, 0, 0);
        }
        int col = nt * 16 + lr;
        #pragma unroll
        for (int j = 0; j < 4; ++j) {
            int row = wv * 16 + lg * 4 + j;          // row = pix_in_group*8 + n
            int n = row & 7, p = row >> 3;
            out_t[n * 1024 + (col ^ n) * 8 + p]        = cvt1(a0[j] + biasc);
            out_t[8192 + n * 1024 + (col ^ n) * 8 + p] = cvt1(a1[j] + biasc);
        }
        if (nt < 7) {
            #pragma unroll
            for (int ks = 0; ks < 4; ++ks) PBc[ks] = PBn[ks];
            biasc = biasn;
        }
    }
    __syncthreads();   // B3: out_t complete

    // ---- epilogue: residual (direct, L2-hot) + out_t, store ----
    #pragma unroll 4
    for (int it = 0; it < 16; ++it) {
        int t = it * 256 + tid;                      // 0..4095
        int pq = t & 3;
        int row = t >> 2;                            // 0..1023 = n*128 + c
        int n = row >> 7, c = row & 127;
        int gaddr = base + (n * CDIM + c) * HWSZ + pq * 4;
        float4 r0 = *(const float4*)(feat + gaddr);
        int p = pq * 4;
        int idx = (p >> 3) * 8192 + n * 1024 + (c ^ n) * 8 + (p & 7);
        uint2 tv = *(const uint2*)(out_t + idx);     // 4 consecutive pixels
        const unsigned short* tp = (const unsigned short*)&tv;
        float4 o;
        o.x = r0.x + bf2f(tp[0]); o.y = r0.y + bf2f(tp[1]);
        o.z = r0.z + bf2f(tp[2]); o.w = r0.w + bf2f(tp[3]);
        *(float4*)(outp + gaddr) = o;
    }
}

extern "C" void kernel_launch(void* const* d_in, const int* in_sizes, int n_in,
                              void* d_out, int out_size, void* d_ws, size_t ws_size,
                              hipStream_t stream) {
    const float* feat  = (const float*)d_in[0];
    const float* wqkv  = (const float*)d_in[1];
    const float* wproj = (const float*)d_in[2];
    const float* bproj = (const float*)d_in[3];
    const float* gamma = (const float*)d_in[4];
    const float* beta  = (const float*)d_in[5];
    unsigned short* ws = (unsigned short*)d_ws;      // needs 131584 B
    float* outp = (float*)d_out;

    hipLaunchKernelGGL(repack_k, dim3(33), dim3(256), 0, stream,
                       wqkv, wproj, gamma, beta, ws);
    hipLaunchKernelGGL(cfa_main, dim3(NBLK), dim3(256), 0, stream,
                       feat, bproj, ws, outp);
}

// Round 16
// 103.594 us; speedup vs baseline: 2.0123x; 2.0123x over previous
//
#include <hip/hip_runtime.h>

#define NFR 8
#define CDIM 128
#define HH 96
#define WW 96
#define NB 4
#define HWSZ 9216        // HH*WW
#define NBLK 2304        // NB*HH*(WW/16)
#define NXCD 8
#define CPX (NBLK / NXCD)  // 288

typedef __attribute__((ext_vector_type(8))) short bf16x8;
typedef __attribute__((ext_vector_type(4))) float f32x4;
typedef __attribute__((ext_vector_type(2))) float f32x2;
typedef __attribute__((ext_vector_type(2))) __bf16 bf16x2;

union FragU { uint4 u; bf16x8 v; };

__device__ inline float bf2f(unsigned short h) {
    unsigned int x = ((unsigned int)h) << 16;
    float f; __builtin_memcpy(&f, &x, 4); return f;
}
__device__ inline unsigned short f2bf(float f) {
    unsigned int x; __builtin_memcpy(&x, &f, 4);
    return (unsigned short)((x + 0x7FFFu + ((x >> 16) & 1u)) >> 16);
}
__device__ inline unsigned int packbf(float a, float b) {
    return (unsigned int)f2bf(a) | ((unsigned int)f2bf(b) << 16);
}
// HW path: compiler emits v_cvt_pk_bf16_f32 (RNE, same results as packbf)
__device__ inline unsigned int cvt2(float a, float b) {
    f32x2 f = {a, b};
    bf16x2 h = __builtin_convertvector(f, bf16x2);
    unsigned int u; __builtin_memcpy(&u, &h, 4); return u;
}
__device__ inline unsigned short cvt1(float a) {
    __bf16 h = (__bf16)a;
    unsigned short s; __builtin_memcpy(&s, &h, 2); return s;
}
// fragment-permutation position of channel-within-32 (even for even c5)
__device__ inline int posmap(int c5) {
    return (c5 < 16) ? (((c5 >> 2) << 3) + (c5 & 3))
                     : ((((c5 & 15) >> 2) << 3) + 4 + (c5 & 3));
}

// ---------------------------------------------------------------------------
// ws layout (uint4 units of 16B):
//   [0,    4096) : qk A-frags   ((hd*2+three)*4+ks)*64 + lane   (three: 0=q,1=k)
//                  q fragments pre-scaled by 0.25 (attention SCALE folded in)
//   [4096, 6144) : v  B-frags   (hd*4+ks)*64 + lane
//   [6144, 8192) : proj B-frags (nt*4+ks)*64 + lane
//   [8192, 8208) : gamma bf16 frags (ks*4+lg), [8208, 8224): beta bf16 frags
// Fragment element e (0..7) of (ks,lg): channel c = ks*32+lg*4+(e&3)+((e>>2)<<4)
// ---------------------------------------------------------------------------
__global__ __launch_bounds__(256)
void repack_k(const float* __restrict__ wqkv, const float* __restrict__ wproj,
              const float* __restrict__ gamma, const float* __restrict__ beta,
              unsigned short* __restrict__ ws)
{
    int gid = blockIdx.x * 256 + threadIdx.x;
    uint4* wsq = (uint4*)ws;
    int l = gid & 63, lr = l & 15, lg = (l >> 4) & 3;
    if (gid < 8192) {
        int unit = gid >> 6;
        int col, ks, stride;
        float scale = 1.0f;
        const float* src;
        if (unit < 64) {              // qk A-frags: A[m=col][k=c] = wqkv[c][col]
            int t = unit >> 2; ks = unit & 3;
            int hd = t >> 1, three = t & 1;
            col = three * 128 + hd * 16 + lr;
            src = wqkv; stride = 384;
            if (three == 0) scale = 0.25f;   // fold SCALE into q
        } else if (unit < 96) {       // v B-frags: B[k=c][n] = wqkv[c][256+hd*16+n]
            int u2 = unit - 64; int hd = u2 >> 2; ks = u2 & 3;
            col = 256 + hd * 16 + lr;
            src = wqkv; stride = 384;
        } else {                      // proj B-frags: B[k=c][n] = wproj[c][n]
            int u3 = unit - 96; int nt = u3 >> 2; ks = u3 & 3;
            col = nt * 16 + lr;
            src = wproj; stride = 128;
        }
        unsigned int dw[4];
        #pragma unroll
        for (int i = 0; i < 4; ++i) {
            int e0 = 2 * i, e1 = 2 * i + 1;
            int c0 = ks * 32 + lg * 4 + (e0 & 3) + ((e0 >> 2) << 4);
            int c1 = ks * 32 + lg * 4 + (e1 & 3) + ((e1 >> 2) << 4);
            dw[i] = packbf(src[c0 * stride + col] * scale, src[c1 * stride + col] * scale);
        }
        uint4 o; o.x = dw[0]; o.y = dw[1]; o.z = dw[2]; o.w = dw[3];
        wsq[gid] = o;
    } else if (gid < 8192 + 32) {
        int t = gid - 8192;           // 0..15 gamma frags, 16..31 beta frags
        int isb = t >> 4;
        int unit = t & 15;
        int ks2 = unit >> 2, lg2 = unit & 3;
        const float* src2 = isb ? beta : gamma;
        unsigned int dw[4];
        #pragma unroll
        for (int i = 0; i < 4; ++i) {
            int e0 = 2 * i, e1 = 2 * i + 1;
            int c0 = ks2 * 32 + lg2 * 4 + (e0 & 3) + ((e0 >> 2) << 4);
            int c1 = ks2 * 32 + lg2 * 4 + (e1 & 3) + ((e1 >> 2) << 4);
            dw[i] = packbf(src2[c0], src2[c1]);
        }
        uint4 o; o.x = dw[0]; o.y = dw[1]; o.z = dw[2]; o.w = dw[3];
        wsq[8192 + t] = o;
    }
}

// all-register attention for one head, one 64-row group (SCALE pre-folded)
__device__ inline f32x4 attn_ov(f32x4 q, f32x4 k, f32x4 v, bool valid) {
    FragU qb, kb, vb;
    qb.u.x = cvt2(q.x, q.y); qb.u.y = cvt2(q.z, q.w); qb.u.z = 0; qb.u.w = 0;
    kb.u.x = cvt2(k.x, k.y); kb.u.y = cvt2(k.z, k.w); kb.u.z = 0; kb.u.w = 0;
    vb.u.x = cvt2(v.x, v.y); vb.u.y = cvt2(v.z, v.w); vb.u.z = 0; vb.u.w = 0;
    f32x4 zz = {0,0,0,0};
    // S^T = K·Q^T (K=16, upper half zero): lane holds S[q=lr][k=lg*4+j]
    f32x4 st = __builtin_amdgcn_mfma_f32_16x16x32_bf16(kb.v, qb.v, zz, 0, 0, 0);
    float sc0 = st.x, sc1 = st.y, sc2 = st.z, sc3 = st.w;
    float m = valid ? fmaxf(fmaxf(sc0, sc1), fmaxf(sc2, sc3)) : -3.0e38f;
    m = fmaxf(m, __shfl_xor(m, 16));
    float e0 = valid ? __expf(sc0 - m) : 0.f, e1 = valid ? __expf(sc1 - m) : 0.f;
    float e2 = valid ? __expf(sc2 - m) : 0.f, e3 = valid ? __expf(sc3 - m) : 0.f;
    float sm = e0 + e1 + e2 + e3; sm += __shfl_xor(sm, 16);
    float inv = 1.f / sm;
    FragU pb;
    pb.u.x = cvt2(valid ? e0 * inv : 0.f, valid ? e1 * inv : 0.f);
    pb.u.y = cvt2(valid ? e2 * inv : 0.f, valid ? e3 * inv : 0.f);
    pb.u.z = 0; pb.u.w = 0;
    // O^T = V^T·P^T: lane holds O[q=lr][d=lg*4+j]
    return __builtin_amdgcn_mfma_f32_16x16x32_bf16(vb.v, pb.v, zz, 0, 0, 0);
}

// in-register LayerNorm over one 64-row group's fragments.
// Row wv*16+lr lives across lanes {lr, lr+16, lr+32, lr+48} (lg=0..3);
// shfl_xor(16)+shfl_xor(32) reduce across the row.
__device__ inline void ln_reg(FragU* xf, const uint4* gf, const uint4* bfr) {
    float s = 0.f, ss = 0.f;
    #pragma unroll
    for (int ks = 0; ks < 4; ++ks) {
        const unsigned short* e = (const unsigned short*)&xf[ks];
        #pragma unroll
        for (int j = 0; j < 8; ++j) { float x = bf2f(e[j]); s += x; ss += x * x; }
    }
    s += __shfl_xor(s, 16); ss += __shfl_xor(ss, 16);
    s += __shfl_xor(s, 32); ss += __shfl_xor(ss, 32);
    float mu = s * (1.f / 128.f);
    float var = ss * (1.f / 128.f) - mu * mu;
    float rstd = rsqrtf(var + 1e-5f);
    float mr = mu * rstd;
    #pragma unroll
    for (int ks = 0; ks < 4; ++ks) {
        const unsigned short* e = (const unsigned short*)&xf[ks];
        const unsigned short* g = (const unsigned short*)&gf[ks];
        const unsigned short* b = (const unsigned short*)&bfr[ks];
        unsigned int dw[4];
        #pragma unroll
        for (int i = 0; i < 4; ++i) {
            float x0 = bf2f(e[2 * i])     * rstd - mr;
            float x1 = bf2f(e[2 * i + 1]) * rstd - mr;
            dw[i] = cvt2(x0 * bf2f(g[2 * i])     + bf2f(b[2 * i]),
                         x1 * bf2f(g[2 * i + 1]) + bf2f(b[2 * i + 1]));
        }
        xf[ks].u.x = dw[0]; xf[ks].u.y = dw[1]; xf[ks].u.z = dw[2]; xf[ks].u.w = dw[3];
    }
}

// global slot index (uint4 units) for weight slot s (0..11) of head hd:
// s 0..7 = qk A-frags, s 8..11 = v B-frags
__device__ inline int wslot(int hd, int s) {
    return (s < 8) ? (hd * 8 + s) * 64 : 4096 + (hd * 4 + (s - 8)) * 64;
}

// ---------------------------------------------------------------------------
// xln LDS: 32KB. Phase A: staged features (2 groups). Phase B (head loop):
// double-buffered weight slices buf0 @u4[512], buf1 @u4[1280] (12KB each).
// Phase C (proj/epilogue): out_t (32KB). Barriers separate the phases.
// ---------------------------------------------------------------------------
__global__ __launch_bounds__(256, 3)
void cfa_main(const float* __restrict__ feat, const float* __restrict__ bproj,
              const unsigned short* __restrict__ ws, float* __restrict__ outp)
{
    __shared__ uint4 xlnU4[2048];                    // 32 KB
    unsigned short* xln16 = (unsigned short*)xlnU4;
    unsigned int*   xln32 = (unsigned int*)xlnU4;

    const int tid = threadIdx.x;
    const int blk = (int)(blockIdx.x % NXCD) * CPX + (int)blockIdx.x / NXCD;
    const int wt = blk % 6, h = (blk / 6) % 96, b = blk / (6 * 96);
    const int base = ((b * NFR) * CDIM) * HWSZ + h * WW + wt * 16;

    // ---- phase 1: stage 16 pixels (raw bf16); 4 lanes per (n,c)-row chunk ----
    #pragma unroll
    for (int it = 0; it < 8; ++it) {
        int t = it * 256 + tid;                      // 0..2047
        int pq = t & 3;
        int pr = t >> 2;                             // 0..511 = n*64 + cpair
        int n = pr >> 6;
        int c = (pr & 63) * 2;                       // even channel
        const float* src = feat + base + (n * CDIM + c) * HWSZ + pq * 4;
        float4 f0 = *(const float4*)src;             // ch c,   px pq*4..pq*4+3
        float4 f1 = *(const float4*)(src + HWSZ);    // ch c+1, same pixels
        int ks = c >> 5;
        int pos = posmap(c & 31);                    // even; pos(c+1)=pos+1
        const float* a0 = (const float*)&f0;
        const float* a1 = (const float*)&f1;
        #pragma unroll
        for (int j = 0; j < 4; ++j) {
            int p = pq * 4 + j;
            int g = p >> 3, pin = p & 7;
            xln32[(g * 8192 + ks * 2048 + (pin * 8 + n) * 32 + pos) >> 1] =
                cvt2(a0[j], a1[j]);
        }
    }
    __syncthreads();                                 // B1: staging visible

    const int wv = tid >> 6, l = tid & 63, lr = l & 15, lg = l >> 4;
    const uint4* wsq = (const uint4*)ws;

    // ---- prefetch head-0 weight slots NOW (L2 latency hides under LN) ----
    uint4 h0s0 = wsq[wslot(0, wv * 3 + 0) + l];
    uint4 h0s1 = wsq[wslot(0, wv * 3 + 1) + l];
    uint4 h0s2 = wsq[wslot(0, wv * 3 + 2) + l];

    // ---- gamma/beta frags ----
    uint4 gf[4], bfx[4];
    #pragma unroll
    for (int ks = 0; ks < 4; ++ks) {
        gf[ks]  = wsq[8192 + ks * 4 + lg];
        bfx[ks] = wsq[8208 + ks * 4 + lg];
    }

    // ---- read raw frags, LayerNorm in registers ----
    FragU xf0[4], xf1[4];
    #pragma unroll
    for (int ks = 0; ks < 4; ++ks) {
        xf0[ks].u = xlnU4[ks * 256 + (wv * 16 + lr) * 4 + lg];
        xf1[ks].u = xlnU4[1024 + ks * 256 + (wv * 16 + lr) * 4 + lg];
    }
    ln_reg(xf0, gf, bfx);
    ln_reg(xf1, gf, bfx);

    __syncthreads();   // B2: all xf reads done -> xlnU4 free for weight dbuf

    // ---- publish head-0 weights into buf0 (prefetched above) ----
    xlnU4[512 + (wv * 3 + 0) * 64 + l] = h0s0;
    xlnU4[512 + (wv * 3 + 1) * 64 + l] = h0s1;
    xlnU4[512 + (wv * 3 + 2) * 64 + l] = h0s2;

    const bool valid = ((lg >> 1) == (lr >> 3));     // same-pixel (q,k) pairs
    FragU pa0[4], pa1[4];
    #pragma unroll
    for (int ks = 0; ks < 4; ++ks) {
        pa0[ks].u.x = 0; pa0[ks].u.y = 0; pa0[ks].u.z = 0; pa0[ks].u.w = 0;
        pa1[ks].u.x = 0; pa1[ks].u.y = 0; pa1[ks].u.z = 0; pa1[ks].u.w = 0;
    }

    // ---- per-head loop: LDS-dbuf weights (global read ONCE per block) ----
    uint4 PBc[4];                                    // proj nt=0 frags (loaded @hd=7)
    float biasc;
    #pragma unroll
    for (int hd = 0; hd < 8; ++hd) {
        __syncthreads();   // staged weights for head hd visible; prev-parity reads done
        const uint4* buf = &xlnU4[(hd & 1) ? 1280 : 512];
        uint4 sn0, sn1, sn2;
        if (hd < 7) {      // issue next head's 3 slot-loads (latency hides under MFMA)
            sn0 = wsq[wslot(hd + 1, wv * 3 + 0) + l];
            sn1 = wsq[wslot(hd + 1, wv * 3 + 1) + l];
            sn2 = wsq[wslot(hd + 1, wv * 3 + 2) + l];
        } else {
            #pragma unroll
            for (int ks = 0; ks < 4; ++ks) PBc[ks] = wsq[6144 + ks * 64 + l];
            biasc = bproj[lr];                       // nt=0: col = lr
        }
        f32x4 q0 = {0,0,0,0}, k0 = {0,0,0,0}, v0 = {0,0,0,0};
        f32x4 q1 = {0,0,0,0}, k1 = {0,0,0,0}, v1 = {0,0,0,0};
        #pragma unroll
        for (int ks = 0; ks < 4; ++ks) {
            FragU A, B, V2;
            A.u  = buf[ks * 64 + l];
            B.u  = buf[(4 + ks) * 64 + l];
            V2.u = buf[(8 + ks) * 64 + l];
            q0 = __builtin_amdgcn_mfma_f32_16x16x32_bf16(A.v,  xf0[ks].v, q0, 0, 0, 0);
            k0 = __builtin_amdgcn_mfma_f32_16x16x32_bf16(B.v,  xf0[ks].v, k0, 0, 0, 0);
            q1 = __builtin_amdgcn_mfma_f32_16x16x32_bf16(A.v,  xf1[ks].v, q1, 0, 0, 0);
            k1 = __builtin_amdgcn_mfma_f32_16x16x32_bf16(B.v,  xf1[ks].v, k1, 0, 0, 0);
            v0 = __builtin_amdgcn_mfma_f32_16x16x32_bf16(xf0[ks].v, V2.v, v0, 0, 0, 0);
            v1 = __builtin_amdgcn_mfma_f32_16x16x32_bf16(xf1[ks].v, V2.v, v1, 0, 0, 0);
        }
        f32x4 o0 = attn_ov(q0, k0, v0, valid);
        f32x4 o1 = attn_ov(q1, k1, v1, valid);
        if ((hd & 1) == 0) {
            pa0[hd >> 1].u.x = cvt2(o0.x, o0.y); pa0[hd >> 1].u.y = cvt2(o0.z, o0.w);
            pa1[hd >> 1].u.x = cvt2(o1.x, o1.y); pa1[hd >> 1].u.y = cvt2(o1.z, o1.w);
        } else {
            pa0[hd >> 1].u.z = cvt2(o0.x, o0.y); pa0[hd >> 1].u.w = cvt2(o0.z, o0.w);
            pa1[hd >> 1].u.z = cvt2(o1.x, o1.y); pa1[hd >> 1].u.w = cvt2(o1.z, o1.w);
        }
        if (hd < 7) {      // publish next head's slots into the other buffer
            int dst = ((hd + 1) & 1) ? 1280 : 512;
            xlnU4[dst + (wv * 3 + 0) * 64 + l] = sn0;
            xlnU4[dst + (wv * 3 + 1) * 64 + l] = sn1;
            xlnU4[dst + (wv * 3 + 2) * 64 + l] = sn2;
        }
    }

    __syncthreads();   // B2b: all dbuf reads done -> xlnU4 reusable as out_t

    // ---- proj GEMM, streamed + prefetched: per nt compute 2 accs -> out_t ----
    unsigned short* out_t = xln16;                   // [g][n][col^n][pix]
    #pragma unroll
    for (int nt = 0; nt < 8; ++nt) {
        uint4 PBn[4]; float biasn;
        if (nt < 7) {
            #pragma unroll
            for (int ks = 0; ks < 4; ++ks) PBn[ks] = wsq[6144 + ((nt + 1) * 4 + ks) * 64 + l];
            biasn = bproj[(nt + 1) * 16 + lr];
        }
        f32x4 a0 = {0,0,0,0}, a1 = {0,0,0,0};
        #pragma unroll
        for (int ks = 0; ks < 4; ++ks) {
            FragU B; B.u = PBc[ks];
            a0 = __builtin_amdgcn_mfma_f32_16x16x32_bf16(pa0[ks].v, B.v, a0, 0, 0, 0);
            a1 = __builtin_amdgcn_mfma_f32_16x16x32_bf16(pa1[ks].v, B.v, a1, 0, 0, 0);
        }
        int col = nt * 16 + lr;
        #pragma unroll
        for (int j = 0; j < 4; ++j) {
            int row = wv * 16 + lg * 4 + j;          // row = pix_in_group*8 + n
            int n = row & 7, p = row >> 3;
            out_t[n * 1024 + (col ^ n) * 8 + p]        = cvt1(a0[j] + biasc);
            out_t[8192 + n * 1024 + (col ^ n) * 8 + p] = cvt1(a1[j] + biasc);
        }
        if (nt < 7) {
            #pragma unroll
            for (int ks = 0; ks < 4; ++ks) PBc[ks] = PBn[ks];
            biasc = biasn;
        }
    }
    __syncthreads();   // B3: out_t complete

    // ---- epilogue: residual (direct, L2-hot) + out_t, store ----
    #pragma unroll 4
    for (int it = 0; it < 16; ++it) {
        int t = it * 256 + tid;                      // 0..4095
        int pq = t & 3;
        int row = t >> 2;                            // 0..1023 = n*128 + c
        int n = row >> 7, c = row & 127;
        int gaddr = base + (n * CDIM + c) * HWSZ + pq * 4;
        float4 r0 = *(const float4*)(feat + gaddr);
        int p = pq * 4;
        int idx = (p >> 3) * 8192 + n * 1024 + (c ^ n) * 8 + (p & 7);
        uint2 tv = *(const uint2*)(out_t + idx);     // 4 consecutive pixels
        const unsigned short* tp = (const unsigned short*)&tv;
        float4 o;
        o.x = r0.x + bf2f(tp[0]); o.y = r0.y + bf2f(tp[1]);
        o.z = r0.z + bf2f(tp[2]); o.w = r0.w + bf2f(tp[3]);
        *(float4*)(outp + gaddr) = o;
    }
}

extern "C" void kernel_launch(void* const* d_in, const int* in_sizes, int n_in,
                              void* d_out, int out_size, void* d_ws, size_t ws_size,
                              hipStream_t stream) {
    const float* feat  = (const float*)d_in[0];
    const float* wqkv  = (const float*)d_in[1];
    const float* wproj = (const float*)d_in[2];
    const float* bproj = (const float*)d_in[3];
    const float* gamma = (const float*)d_in[4];
    const float* beta  = (const float*)d_in[5];
    unsigned short* ws = (unsigned short*)d_ws;      // needs 131584 B
    float* outp = (float*)d_out;

    hipLaunchKernelGGL(repack_k, dim3(33), dim3(256), 0, stream,
                       wqkv, wproj, gamma, beta, ws);
    hipLaunchKernelGGL(cfa_main, dim3(NBLK), dim3(256), 0, stream,
                       feat, bproj, ws, outp);
}